// Round 1
// baseline (567.408 us; speedup 1.0000x reference)
//
#include <hip/hip_runtime.h>

// PowerSpectrum: out[n, l*512 + q*16 + p] = (1/sqrt(2l+1)) * sum_m x_nu[l,n,m,q] * x_1[l,n,m,p]
// L=4, M=7, F_NU=32, F_1=16. Memory-bound (678 MB traffic vs 1.43 GFLOP).

constexpr int L_DIM  = 4;
constexpr int M_DIM  = 7;
constexpr int FNU    = 32;
constexpr int F1     = 16;
constexpr int XNU_W  = L_DIM * M_DIM * FNU;   // 896 floats per sample
constexpr int X1_W   = L_DIM * M_DIM * F1;    // 448 floats per sample
constexpr int SAMP_W = XNU_W + X1_W;          // 1344 floats per sample
constexpr int OUT_W  = L_DIM * FNU * F1;      // 2048 floats per sample

__global__ __launch_bounds__(256) void ps_kernel(
    const float* __restrict__ x_nu,
    const float* __restrict__ x_1,
    float* __restrict__ out,
    int N)
{
    __shared__ float lds[2 * SAMP_W];           // 10752 B
    const int t  = threadIdx.x;
    const int n0 = blockIdx.x * 2;

    const float4* __restrict__ xnu4 = reinterpret_cast<const float4*>(x_nu);
    const float4* __restrict__ x14  = reinterpret_cast<const float4*>(x_1);
    float4* lds4 = reinterpret_cast<float4*>(lds);

    // Stage 2 samples: 672 float4 total (per sample: 224 x_nu + 112 x_1 float4s).
    // Per (l,n) the global data is a contiguous chunk (56 or 28 float4s) -> coalesced.
    #pragma unroll
    for (int ii = 0; ii < 3; ++ii) {
        int i = t + ii * 256;
        if (i < 2 * 336) {
            int s = (i >= 336) ? 1 : 0;
            int r = i - s * 336;
            int n = n0 + s;
            if (n < N) {
                float4 v; int dst;
                if (r < 224) {                       // x_nu part
                    int l = r / 56, off = r - l * 56;
                    v   = xnu4[(size_t)(l * N + n) * 56 + off];
                    dst = s * (SAMP_W / 4) + l * 56 + off;
                } else {                             // x_1 part
                    int r2 = r - 224;
                    int l = r2 / 28, off = r2 - l * 28;
                    v   = x14[(size_t)(l * N + n) * 28 + off];
                    dst = s * (SAMP_W / 4) + (XNU_W / 4) + l * 28 + off;
                }
                lds4[dst] = v;
            }
        }
    }
    __syncthreads();

    // Thread -> (sample s, channel l, 4q x 4p register tile)
    const int s  = t >> 7;          // 0..1
    const int u7 = t & 127;
    const int l  = u7 >> 5;         // 0..3
    const int u  = u7 & 31;
    const int pb = (u & 3) * 4;     // p base: 0,4,8,12
    const int q2 = u >> 2;          // 0..7 ; q = q2 + 8k

    const int n = n0 + s;
    if (n >= N) return;

    const float* xnu_s = lds + s * SAMP_W + l * (M_DIM * FNU);
    const float* x1_s  = lds + s * SAMP_W + XNU_W + l * (M_DIM * F1);

    float acc[4][4];
    #pragma unroll
    for (int k = 0; k < 4; ++k)
        #pragma unroll
        for (int j = 0; j < 4; ++j) acc[k][j] = 0.0f;

    #pragma unroll
    for (int m = 0; m < M_DIM; ++m) {
        float4 b = *reinterpret_cast<const float4*>(&x1_s[m * F1 + pb]);  // ds_read_b128
        float a[4];
        #pragma unroll
        for (int k = 0; k < 4; ++k) a[k] = xnu_s[m * FNU + q2 + 8 * k];   // ds_read_b32 x4
        #pragma unroll
        for (int k = 0; k < 4; ++k) {
            acc[k][0] += a[k] * b.x;
            acc[k][1] += a[k] * b.y;
            acc[k][2] += a[k] * b.z;
            acc[k][3] += a[k] * b.w;
        }
    }

    const float scale = rsqrtf(2.0f * (float)l + 1.0f);  // cg[l]
    float* outp = out + (size_t)n * OUT_W + l * (FNU * F1);
    #pragma unroll
    for (int k = 0; k < 4; ++k) {
        int q = q2 + 8 * k;
        float4 v = make_float4(acc[k][0] * scale, acc[k][1] * scale,
                               acc[k][2] * scale, acc[k][3] * scale);
        // wave store covers two contiguous 512B runs -> fully coalesced
        *reinterpret_cast<float4*>(&outp[q * F1 + pb]) = v;
    }
}

extern "C" void kernel_launch(void* const* d_in, const int* in_sizes, int n_in,
                              void* d_out, int out_size, void* d_ws, size_t ws_size,
                              hipStream_t stream) {
    const float* x_nu = (const float*)d_in[0];
    const float* x_1  = (const float*)d_in[1];
    float* out = (float*)d_out;
    const int N = in_sizes[0] / XNU_W;   // 50000
    const int blocks = (N + 1) / 2;      // 2 samples per block
    ps_kernel<<<blocks, 256, 0, stream>>>(x_nu, x_1, out, N);
}